// Round 1
// baseline (181.733 us; speedup 1.0000x reference)
//
#include <hip/hip_runtime.h>

#define B_  256
#define I_  1152
#define KIN 8
#define N_  10
#define O_  16
#define P_  9216      // KIN * I_
#define NO_ 160       // N_ * O_

typedef short s8v __attribute__((ext_vector_type(8)));
typedef float f4v __attribute__((ext_vector_type(4)));

__device__ inline float bf2f(unsigned short u){
  unsigned v = ((unsigned)u) << 16; float f; __builtin_memcpy(&f, &v, 4); return f;
}
__device__ inline unsigned short f2bf(float f){
  unsigned b; __builtin_memcpy(&b, &f, 4);
  b += 0x7fffu + ((b >> 16) & 1u);   // RNE
  return (unsigned short)(b >> 16);
}

// ---------------------------------------------------------------------------
// prep_x: cast x (fp32, [b][p], p=k*1152+i) to bf16 in BOTH layouts:
//   xbp[b][p] (GEMM-S A operand), xpb[p][b] (GEMM-G A operand, via LDS tile)
// grid 2304 (8 b-tiles x 288 p-tiles), block 256
__global__ void prep_x(const float* __restrict__ x, unsigned short* __restrict__ xbp,
                       unsigned short* __restrict__ xpb){
  __shared__ float tile[32][36];
  int tb = blockIdx.x & 7, tp = blockIdx.x >> 3;
  int b0 = tb << 5, p0 = tp << 5;
  int t = threadIdx.x;
  int r = t >> 3, c4 = (t & 7) << 2;
  float4 v = *reinterpret_cast<const float4*>(x + (size_t)(b0 + r)*P_ + p0 + c4);
  *reinterpret_cast<float4*>(&tile[r][c4]) = v;
  uint2 pk;
  pk.x = (unsigned)f2bf(v.x) | ((unsigned)f2bf(v.y) << 16);
  pk.y = (unsigned)f2bf(v.z) | ((unsigned)f2bf(v.w) << 16);
  *reinterpret_cast<uint2*>(xbp + (size_t)(b0 + r)*P_ + p0 + c4) = pk;
  __syncthreads();
  int pr = r, bc = c4;
  float f0 = tile[bc+0][pr], f1 = tile[bc+1][pr], f2 = tile[bc+2][pr], f3 = tile[bc+3][pr];
  uint2 pk2;
  pk2.x = (unsigned)f2bf(f0) | ((unsigned)f2bf(f1) << 16);
  pk2.y = (unsigned)f2bf(f2) | ((unsigned)f2bf(f3) << 16);
  *reinterpret_cast<uint2*>(xpb + (size_t)(p0 + pr)*B_ + b0 + bc) = pk2;
}

// ---------------------------------------------------------------------------
// prep_W: W[i][n][o][k] fp32 -> Wt[q=n*16+o][p=k*1152+i] = bf16(0.03*W)
//         and At (iteration-1 effective weight, c uniform = 0.1) = bf16(0.003*W)
// grid 160 (one block per q), block 256
__global__ void prep_W(const float* __restrict__ W, unsigned short* __restrict__ Wt,
                       unsigned short* __restrict__ At){
  int q = blockIdx.x;
  int n = q >> 4, o = q & 15;
  int t = threadIdx.x;
  for (int i0 = 0; i0 < I_; i0 += 256){
    int i = i0 + t;
    if (i < I_){
      const float* src = W + (size_t)i*1280 + n*128 + o*8;
      float4 a = *reinterpret_cast<const float4*>(src);
      float4 b = *reinterpret_cast<const float4*>(src + 4);
      float vv[8] = {a.x,a.y,a.z,a.w,b.x,b.y,b.z,b.w};
      #pragma unroll
      for (int k = 0; k < 8; ++k){
        size_t addr = (size_t)q*P_ + (size_t)k*I_ + i;
        float wv = vv[k] * 0.03f;
        Wt[addr] = f2bf(wv);
        At[addr] = f2bf(wv * 0.1f);
      }
    }
  }
}

// ---------------------------------------------------------------------------
// gemm_s: s_part[kc][b][q] = sum_p xbp[b][p] * At[q][p]   (MFMA 16x16x32 bf16)
// grid (16 m-tiles, 10 n, 4 k-chunks), block 64 (1 wave = one 16x16 C tile)
__global__ void gemm_s(const unsigned short* __restrict__ xbp,
                       const unsigned short* __restrict__ At,
                       float* __restrict__ s_part){
  int l = threadIdx.x;
  int b0 = blockIdx.x << 4;
  int n  = blockIdx.y;
  int kc = blockIdx.z;
  int lo = l & 15, quad = l >> 4;
  const unsigned short* ap = xbp + (size_t)(b0 + lo)*P_ + kc*2304 + quad*8;
  const unsigned short* bp = At  + (size_t)(n*16 + lo)*P_ + kc*2304 + quad*8;
  f4v acc = {0.f, 0.f, 0.f, 0.f};
  for (int s = 0; s < 72; ++s){
    s8v a = *reinterpret_cast<const s8v*>(ap);
    s8v b = *reinterpret_cast<const s8v*>(bp);
    acc = __builtin_amdgcn_mfma_f32_16x16x32_bf16(a, b, acc, 0, 0, 0);
    ap += 32; bp += 32;
  }
  float* out = s_part + (size_t)kc*40960;
  int r0 = quad << 2;
  #pragma unroll
  for (int r = 0; r < 4; ++r)
    out[(size_t)(b0 + r0 + r)*NO_ + n*16 + lo] = acc[r];
}

// ---------------------------------------------------------------------------
// squash_k: sum 4 split-K partials, squash over O per (b,n) row (16-lane
// shuffle reduce), write fp32 v; optionally also bf16 v^T[q][b] for GEMM-G.
// grid 160, block 256 (16 rows/block)
__global__ void squash_k(const float* __restrict__ s_part, float* __restrict__ vout,
                         unsigned short* __restrict__ vbt, int write_bf){
  int t = threadIdx.x;
  int o = t & 15, rl = t >> 4;
  int rowid = blockIdx.x*16 + rl;          // b*10+n
  int b = rowid / 10, n = rowid - b*10;
  size_t idx = (size_t)b*NO_ + n*16 + o;
  float sv = s_part[idx] + s_part[idx + 40960] + s_part[idx + 81920] + s_part[idx + 122880];
  float sq = sv * sv;
  #pragma unroll
  for (int m = 8; m >= 1; m >>= 1) sq += __shfl_xor(sq, m, 16);
  float mag = sqrtf(sq);
  float outv = sv * mag / (1.0f + sq);
  vout[idx] = outv;
  if (write_bf) vbt[(size_t)(n*16 + o)*B_ + b] = f2bf(outv);
}

// ---------------------------------------------------------------------------
// gemm_g: G[p][q] = sum_b xpb[p][b] * vbt[q][b], stored permuted into W's own
// layout G2[i][n][o][k] so the contraction reads two contiguous 128-f rows.
// grid 5760 (576 p-tiles x 10 q-tiles), block 64
__global__ void gemm_g(const unsigned short* __restrict__ xpb,
                       const unsigned short* __restrict__ vbt,
                       float* __restrict__ G2){
  int l = threadIdx.x;
  int pt = blockIdx.x % 576, qt = blockIdx.x / 576;
  int p0 = pt << 4, q0 = qt << 4;
  int lo = l & 15, quad = l >> 4;
  const unsigned short* ap = xpb + (size_t)(p0 + lo)*B_ + quad*8;
  const unsigned short* bp = vbt + (size_t)(q0 + lo)*B_ + quad*8;
  f4v acc = {0.f, 0.f, 0.f, 0.f};
  #pragma unroll
  for (int s = 0; s < 8; ++s){
    s8v a = *reinterpret_cast<const s8v*>(ap);
    s8v b = *reinterpret_cast<const s8v*>(bp);
    acc = __builtin_amdgcn_mfma_f32_16x16x32_bf16(a, b, acc, 0, 0, 0);
    ap += 32; bp += 32;
  }
  int k  = p0 / 1152;                      // constant within a p-tile (1152 % 16 == 0)
  int ib = p0 - k*1152;
  int r0 = quad << 2;
  #pragma unroll
  for (int r = 0; r < 4; ++r){
    int i = ib + r0 + r;
    G2[(size_t)i*1280 + (size_t)(q0 + lo)*8 + k] = acc[r];
  }
}

// ---------------------------------------------------------------------------
// routing_update: bij[i][n] (+)= (0.03/256) * dot128(W[i][n], G2[i][n]);
// softmax over n (16-lane groups, n>=10 masked); then materialize next-iter
// effective weight At[q][p] = c[i][n] * Wt[q][p] for this block's 16 i's.
// grid 72, block 256
__global__ void routing_update(const float* __restrict__ W, const float* __restrict__ G2,
                               float* __restrict__ bij, const unsigned short* __restrict__ Wt,
                               unsigned short* __restrict__ At, int accumulate){
  __shared__ float c_s[16][17];
  int t = threadIdx.x;
  int n = t & 15, il = t >> 4;
  int i = blockIdx.x*16 + il;
  float nb = -INFINITY;
  if (n < N_){
    const float* wr = W  + (size_t)i*1280 + n*128;
    const float* gr = G2 + (size_t)i*1280 + n*128;
    float dot = 0.f;
    #pragma unroll 8
    for (int j = 0; j < 32; ++j){
      float4 wv = *reinterpret_cast<const float4*>(wr + 4*j);
      float4 gv = *reinterpret_cast<const float4*>(gr + 4*j);
      dot += wv.x*gv.x + wv.y*gv.y + wv.z*gv.z + wv.w*gv.w;
    }
    dot *= (0.03f / 256.f);
    if (accumulate) dot += bij[i*N_ + n];
    bij[i*N_ + n] = dot;
    nb = dot;
  }
  float mx = nb;
  #pragma unroll
  for (int m = 8; m >= 1; m >>= 1) mx = fmaxf(mx, __shfl_xor(mx, m, 16));
  float e = (n < N_) ? expf(nb - mx) : 0.f;
  float se = e;
  #pragma unroll
  for (int m = 8; m >= 1; m >>= 1) se += __shfl_xor(se, m, 16);
  c_s[il][n] = e / se;
  __syncthreads();
  int i0 = blockIdx.x * 16;
  for (int e2 = 0; e2 < 80; ++e2){
    int gid = t + e2*256;                  // (((n*16+o)*8)+k)*16+il, 20480 total
    int ill = gid & 15, k = (gid >> 4) & 7, o = (gid >> 7) & 15, nn = gid >> 11;
    size_t addr = (size_t)(nn*16 + o)*P_ + (size_t)k*I_ + i0 + ill;
    At[addr] = f2bf(bf2f(Wt[addr]) * c_s[ill][nn]);
  }
}

// ---------------------------------------------------------------------------
extern "C" void kernel_launch(void* const* d_in, const int* in_sizes, int n_in,
                              void* d_out, int out_size, void* d_ws, size_t ws_size,
                              hipStream_t stream){
  (void)in_sizes; (void)n_in; (void)out_size; (void)ws_size;
  const float* x = (const float*)d_in[0];   // (256, 8, 1152)
  const float* W = (const float*)d_in[1];   // (1, 1152, 10, 16, 8)
  float* out = (float*)d_out;               // (256, 10, 16, 1)

  // workspace carve-up (fp32 region then bf16 region, all 16B aligned)
  float* s_part = (float*)d_ws;             // 4 * 40960
  float* v_ws   = s_part + 4*40960;         // 40960
  float* bij    = v_ws + 40960;             // 11520
  float* G2     = bij + 11520;              // 1474560
  unsigned short* xbp = (unsigned short*)(G2 + 1474560); // 2359296
  unsigned short* xpb = xbp + 2359296;                   // 2359296
  unsigned short* Wt  = xpb + 2359296;                   // 1474560
  unsigned short* At  = Wt  + 1474560;                   // 1474560
  unsigned short* vbt = At  + 1474560;                   // 40960

  prep_x<<<2304, 256, 0, stream>>>(x, xbp, xpb);
  prep_W<<<160, 256, 0, stream>>>(W, Wt, At);

  for (int it = 0; it < 3; ++it){
    gemm_s<<<dim3(16, 10, 4), 64, 0, stream>>>(xbp, At, s_part);
    if (it < 2){
      squash_k<<<160, 256, 0, stream>>>(s_part, v_ws, vbt, 1);
      gemm_g<<<5760, 64, 0, stream>>>(xpb, vbt, G2);
      routing_update<<<72, 256, 0, stream>>>(W, G2, bij, Wt, At, it);
    } else {
      squash_k<<<160, 256, 0, stream>>>(s_part, out, vbt, 0);
    }
  }
}

// Round 2
// 158.124 us; speedup vs baseline: 1.1493x; 1.1493x over previous
//
#include <hip/hip_runtime.h>

#define B_  256
#define I_  1152
#define KIN 8
#define N_  10
#define O_  16
#define P_  9216      // KIN * I_
#define NO_ 160       // N_ * O_

typedef short s8v __attribute__((ext_vector_type(8)));
typedef float f4v __attribute__((ext_vector_type(4)));

__device__ inline float bf2f(unsigned short u){
  unsigned v = ((unsigned)u) << 16; float f; __builtin_memcpy(&f, &v, 4); return f;
}
__device__ inline unsigned short f2bf(float f){
  unsigned b; __builtin_memcpy(&b, &f, 4);
  b += 0x7fffu + ((b >> 16) & 1u);   // RNE
  return (unsigned short)(b >> 16);
}

// ---------------------------------------------------------------------------
// prep_all: fused input-cast kernel.
//   blocks [0,160):   W[i][n][o][k] fp32 -> Wt[q=n*16+o][p=k*1152+i] = bf16(0.03*W)
//                     and At (iter-0 effective weight, c uniform=0.1) = bf16(0.003*W)
//   blocks [160,2464): x fp32 [b][p] -> bf16 xbp[b][p] and xpb[p][b] (LDS transpose)
// block 256
__global__ void prep_all(const float* __restrict__ x, const float* __restrict__ W,
                         unsigned short* __restrict__ xbp, unsigned short* __restrict__ xpb,
                         unsigned short* __restrict__ Wt, unsigned short* __restrict__ At){
  __shared__ float tile[32][36];
  int t = threadIdx.x;
  if (blockIdx.x < 160){
    int q = blockIdx.x;
    int n = q >> 4, o = q & 15;
    for (int i0 = 0; i0 < I_; i0 += 256){
      int i = i0 + t;
      if (i < I_){
        const float* src = W + (size_t)i*1280 + n*128 + o*8;
        float4 a = *reinterpret_cast<const float4*>(src);
        float4 b = *reinterpret_cast<const float4*>(src + 4);
        float vv[8] = {a.x,a.y,a.z,a.w,b.x,b.y,b.z,b.w};
        #pragma unroll
        for (int k = 0; k < 8; ++k){
          size_t addr = (size_t)q*P_ + (size_t)k*I_ + i;
          float wv = vv[k] * 0.03f;
          Wt[addr] = f2bf(wv);
          At[addr] = f2bf(wv * 0.1f);
        }
      }
    }
  } else {
    int bid = blockIdx.x - 160;
    int tb = bid & 7, tp = bid >> 3;
    int b0 = tb << 5, p0 = tp << 5;
    int r = t >> 3, c4 = (t & 7) << 2;
    float4 v = *reinterpret_cast<const float4*>(x + (size_t)(b0 + r)*P_ + p0 + c4);
    *reinterpret_cast<float4*>(&tile[r][c4]) = v;
    uint2 pk;
    pk.x = (unsigned)f2bf(v.x) | ((unsigned)f2bf(v.y) << 16);
    pk.y = (unsigned)f2bf(v.z) | ((unsigned)f2bf(v.w) << 16);
    *reinterpret_cast<uint2*>(xbp + (size_t)(b0 + r)*P_ + p0 + c4) = pk;
    __syncthreads();
    int pr = r, bc = c4;
    float f0 = tile[bc+0][pr], f1 = tile[bc+1][pr], f2 = tile[bc+2][pr], f3 = tile[bc+3][pr];
    uint2 pk2;
    pk2.x = (unsigned)f2bf(f0) | ((unsigned)f2bf(f1) << 16);
    pk2.y = (unsigned)f2bf(f2) | ((unsigned)f2bf(f3) << 16);
    *reinterpret_cast<uint2*>(xpb + (size_t)(p0 + pr)*B_ + b0 + bc) = pk2;
  }
}

// ---------------------------------------------------------------------------
// gemm_s: s_part[kc][b][q] = sum_p xbp[b][p] * At[q][p]   (MFMA 16x16x32 bf16)
// split-K 16 (576 p each = 18 k-steps), dual accumulators to halve dep chain.
// grid (16, 10, 16), block 64 (1 wave per 16x16 C tile)
__global__ void gemm_s(const unsigned short* __restrict__ xbp,
                       const unsigned short* __restrict__ At,
                       float* __restrict__ s_part){
  int l = threadIdx.x;
  int b0 = blockIdx.x << 4;
  int n  = blockIdx.y;
  int kc = blockIdx.z;
  int lo = l & 15, quad = l >> 4;
  const s8v* ap = reinterpret_cast<const s8v*>(xbp + (size_t)(b0 + lo)*P_ + kc*576 + quad*8);
  const s8v* bp = reinterpret_cast<const s8v*>(At  + (size_t)(n*16 + lo)*P_ + kc*576 + quad*8);
  f4v acc0 = {0.f,0.f,0.f,0.f}, acc1 = {0.f,0.f,0.f,0.f};
  #pragma unroll
  for (int s = 0; s < 9; ++s){
    s8v a0 = ap[8*s];     // step 2s:   advance 32 shorts = 4 s8v
    s8v b0v = bp[8*s];
    s8v a1 = ap[8*s + 4];
    s8v b1v = bp[8*s + 4];
    acc0 = __builtin_amdgcn_mfma_f32_16x16x32_bf16(a0, b0v, acc0, 0, 0, 0);
    acc1 = __builtin_amdgcn_mfma_f32_16x16x32_bf16(a1, b1v, acc1, 0, 0, 0);
  }
  f4v acc = acc0 + acc1;
  float* out = s_part + (size_t)kc*40960;
  int r0 = quad << 2;
  #pragma unroll
  for (int r = 0; r < 4; ++r)
    out[(size_t)(b0 + r0 + r)*NO_ + n*16 + lo] = acc[r];
}

// ---------------------------------------------------------------------------
// squash_k: sum 16 split-K partials, squash over O per (b,n) row (16-lane
// shuffle reduce), write fp32 v; optionally also bf16 v^T[q][b] for GEMM-G.
// grid 160, block 256 (16 rows/block)
__global__ void squash_k(const float* __restrict__ s_part, float* __restrict__ vout,
                         unsigned short* __restrict__ vbt, int write_bf){
  int t = threadIdx.x;
  int o = t & 15, rl = t >> 4;
  int rowid = blockIdx.x*16 + rl;          // b*10+n
  int b = rowid / 10, n = rowid - b*10;
  size_t idx = (size_t)b*NO_ + n*16 + o;
  float sv = 0.f;
  #pragma unroll
  for (int c = 0; c < 16; ++c) sv += s_part[idx + (size_t)c*40960];
  float sq = sv * sv;
  #pragma unroll
  for (int m = 8; m >= 1; m >>= 1) sq += __shfl_xor(sq, m, 16);
  float mag = sqrtf(sq);
  float outv = sv * mag / (1.0f + sq);
  vout[idx] = outv;
  if (write_bf) vbt[(size_t)(n*16 + o)*B_ + b] = f2bf(outv);
}

// ---------------------------------------------------------------------------
// gemm_g: G[p][q] = sum_b xpb[p][b] * vbt[q][b], stored permuted into W's own
// layout G2[i][n][o][k] so the dot kernel reads two contiguous 128-f rows.
// grid 5760 (576 p-tiles x 10 q-tiles), block 64
__global__ void gemm_g(const unsigned short* __restrict__ xpb,
                       const unsigned short* __restrict__ vbt,
                       float* __restrict__ G2){
  int l = threadIdx.x;
  int pt = blockIdx.x % 576, qt = blockIdx.x / 576;
  int p0 = pt << 4, q0 = qt << 4;
  int lo = l & 15, quad = l >> 4;
  const s8v* ap = reinterpret_cast<const s8v*>(xpb + (size_t)(p0 + lo)*B_ + quad*8);
  const s8v* bp = reinterpret_cast<const s8v*>(vbt + (size_t)(q0 + lo)*B_ + quad*8);
  f4v acc0 = {0.f,0.f,0.f,0.f}, acc1 = {0.f,0.f,0.f,0.f};
  #pragma unroll
  for (int s = 0; s < 4; ++s){
    s8v a0 = ap[8*s];
    s8v b0v = bp[8*s];
    s8v a1 = ap[8*s + 4];
    s8v b1v = bp[8*s + 4];
    acc0 = __builtin_amdgcn_mfma_f32_16x16x32_bf16(a0, b0v, acc0, 0, 0, 0);
    acc1 = __builtin_amdgcn_mfma_f32_16x16x32_bf16(a1, b1v, acc1, 0, 0, 0);
  }
  f4v acc = acc0 + acc1;
  int k  = p0 / 1152;                      // constant within a p-tile (1152 % 16 == 0)
  int ib = p0 - k*1152;
  int r0 = quad << 2;
  #pragma unroll
  for (int r = 0; r < 4; ++r){
    int i = ib + r0 + r;
    G2[(size_t)i*1280 + (size_t)(q0 + lo)*8 + k] = acc[r];
  }
}

// ---------------------------------------------------------------------------
// dots_softmax: bij[i][n] (+)= (0.03/256) * dot128(W[i][n], G2[i][n]);
// softmax over n; write c transposed: c_t[n][i].
// grid 288 (4 i per block), block 320 (40 groups x 8 lanes; 8 lanes per dot)
__global__ void dots_softmax(const float* __restrict__ W, const float* __restrict__ G2,
                             float* __restrict__ bij, float* __restrict__ c_t,
                             int accumulate){
  __shared__ float ds[40];
  int t = threadIdx.x;
  int g = t >> 3, j = t & 7;
  int il = g / 10, n = g - il*10;
  int i = blockIdx.x*4 + il;
  const float* wr = W  + (size_t)i*1280 + n*128;
  const float* gr = G2 + (size_t)i*1280 + n*128;
  float dot = 0.f;
  #pragma unroll
  for (int m = 0; m < 4; ++m){
    float4 wv = *reinterpret_cast<const float4*>(wr + (j + 8*m)*4);
    float4 gv = *reinterpret_cast<const float4*>(gr + (j + 8*m)*4);
    dot += wv.x*gv.x + wv.y*gv.y + wv.z*gv.z + wv.w*gv.w;
  }
  dot += __shfl_xor(dot, 4, 8);
  dot += __shfl_xor(dot, 2, 8);
  dot += __shfl_xor(dot, 1, 8);
  if (j == 0){
    float v = dot * (0.03f / 256.f);
    if (accumulate) v += bij[i*N_ + n];
    bij[i*N_ + n] = v;
    ds[g] = v;
  }
  __syncthreads();
  if (t < 4){
    int ii = blockIdx.x*4 + t;
    float mx = -1e30f;
    #pragma unroll
    for (int nn = 0; nn < N_; ++nn) mx = fmaxf(mx, ds[t*N_ + nn]);
    float e[N_], se = 0.f;
    #pragma unroll
    for (int nn = 0; nn < N_; ++nn){ e[nn] = expf(ds[t*N_ + nn] - mx); se += e[nn]; }
    float inv = 1.f / se;
    #pragma unroll
    for (int nn = 0; nn < N_; ++nn) c_t[nn*I_ + ii] = e[nn] * inv;
  }
}

// ---------------------------------------------------------------------------
// at_mat: At[q][p] = Wt[q][p] * c_t[n][i] with n=q>>4, i=p%1152. Fully
// coalesced: each thread 8 contiguous elements (16B read, 2x16B c, 16B write).
// grid 720, block 256
__global__ void at_mat(const unsigned short* __restrict__ Wt,
                       const float* __restrict__ c_t,
                       unsigned short* __restrict__ At){
  int tid = blockIdx.x*256 + threadIdx.x;
  int base = tid * 8;
  int q = base / P_;
  int rem = base - q*P_;
  int k = rem / I_;
  int i0 = rem - k*I_;
  int n = q >> 4;
  uint4 w = *reinterpret_cast<const uint4*>(Wt + base);
  float4 c0 = *reinterpret_cast<const float4*>(c_t + n*I_ + i0);
  float4 c1 = *reinterpret_cast<const float4*>(c_t + n*I_ + i0 + 4);
  uint4 r;
  r.x = (unsigned)f2bf(bf2f(w.x & 0xffff) * c0.x) | ((unsigned)f2bf(bf2f(w.x >> 16) * c0.y) << 16);
  r.y = (unsigned)f2bf(bf2f(w.y & 0xffff) * c0.z) | ((unsigned)f2bf(bf2f(w.y >> 16) * c0.w) << 16);
  r.z = (unsigned)f2bf(bf2f(w.z & 0xffff) * c1.x) | ((unsigned)f2bf(bf2f(w.z >> 16) * c1.y) << 16);
  r.w = (unsigned)f2bf(bf2f(w.w & 0xffff) * c1.z) | ((unsigned)f2bf(bf2f(w.w >> 16) * c1.w) << 16);
  *reinterpret_cast<uint4*>(At + base) = r;
}

// ---------------------------------------------------------------------------
extern "C" void kernel_launch(void* const* d_in, const int* in_sizes, int n_in,
                              void* d_out, int out_size, void* d_ws, size_t ws_size,
                              hipStream_t stream){
  (void)in_sizes; (void)n_in; (void)out_size; (void)ws_size;
  const float* x = (const float*)d_in[0];   // (256, 8, 1152)
  const float* W = (const float*)d_in[1];   // (1, 1152, 10, 16, 8)
  float* out = (float*)d_out;               // (256, 10, 16, 1)

  // workspace carve-up (fp32 region then bf16 region, all 16B aligned)
  float* s_part = (float*)d_ws;             // 16 * 40960
  float* v_ws   = s_part + 16*40960;        // 40960
  float* bij    = v_ws + 40960;             // 11520
  float* c_t    = bij + 11520;              // 11520
  float* G2     = c_t + 11520;              // 1474560
  unsigned short* xbp = (unsigned short*)(G2 + 1474560); // 2359296
  unsigned short* xpb = xbp + 2359296;                   // 2359296
  unsigned short* Wt  = xpb + 2359296;                   // 1474560
  unsigned short* At  = Wt  + 1474560;                   // 1474560
  unsigned short* vbt = At  + 1474560;                   // 40960

  prep_all<<<2464, 256, 0, stream>>>(x, W, xbp, xpb, Wt, At);

  for (int it = 0; it < 3; ++it){
    gemm_s<<<dim3(16, 10, 16), 64, 0, stream>>>(xbp, At, s_part);
    if (it < 2){
      squash_k<<<160, 256, 0, stream>>>(s_part, v_ws, vbt, 1);
      gemm_g<<<5760, 64, 0, stream>>>(xpb, vbt, G2);
      dots_softmax<<<288, 320, 0, stream>>>(W, G2, bij, c_t, it);
      at_mat<<<720, 256, 0, stream>>>(Wt, c_t, At);
    } else {
      squash_k<<<160, 256, 0, stream>>>(s_part, out, vbt, 0);
    }
  }
}